// Round 1
// baseline (731.662 us; speedup 1.0000x reference)
//
#include <hip/hip_runtime.h>
#include <hip/hip_bf16.h>

// Problem constants
#define H_IN   128
#define W_IN   128
#define B_SZ   64
#define CONV_O 126            // (128-2)
#define K_DIM  15876          // 126*126
#define N_TRI  8256           // 128*129/2
#define N_OUT  128
#define BK     32
#define BN     64
#define NSTEPS 497            // ceil(15876/32)
#define K8     1988           // NSTEPS*4 groups of 8 k-elements (zero-padded)
#define KSPLIT 16

typedef short  short8  __attribute__((ext_vector_type(8)));
typedef float  floatx4 __attribute__((ext_vector_type(4)));

__device__ inline short f2bf(float f) {
    union { __hip_bfloat16 h; short s; } u;
    u.h = __float2bfloat16(f);
    return u.s;
}

// ---------------------------------------------------------------------------
// Kernel 1: fused conv1(3x3,1->4)+bias+relu -> conv2(1x1,4->1)+bias.
// Output h pre-swizzled into MFMA A-fragment order:
//   hsw[k8][m][j]  (k8 = p>>3, j = p&7, m = batch), zero-padded for p>=K_DIM.
// ---------------------------------------------------------------------------
__global__ __launch_bounds__(256) void conv_kernel(
    const float* __restrict__ x,    // [64][1][128][128]
    const float* __restrict__ w1,   // [4][1][3][3]
    const float* __restrict__ b1,   // [4]
    const float* __restrict__ w2,   // [1][4][1][1]
    const float* __restrict__ b2,   // [1]
    unsigned short* __restrict__ hsw) // [K8][64][8] bf16
{
    int t = blockIdx.x * 256 + threadIdx.x;      // < K8*64*8
    int j  = t & 7;
    int m  = (t >> 3) & 63;
    int k8 = t >> 9;
    int p  = k8 * 8 + j;
    float val = 0.f;
    if (p < K_DIM) {
        int oy = p / CONV_O;
        int ox = p - oy * CONV_O;
        const float* xb = x + m * (H_IN * W_IN) + oy * W_IN + ox;
        float xin[9];
#pragma unroll
        for (int dy = 0; dy < 3; ++dy)
#pragma unroll
            for (int dx = 0; dx < 3; ++dx)
                xin[dy * 3 + dx] = xb[dy * W_IN + dx];
        float acc = b2[0];
#pragma unroll
        for (int c = 0; c < 4; ++c) {
            float s = b1[c];
#pragma unroll
            for (int q = 0; q < 9; ++q) s = fmaf(w1[c * 9 + q], xin[q], s);
            s = fmaxf(s, 0.f);
            acc = fmaf(w2[c], s, acc);
        }
        val = acc;
    }
    hsw[t] = (unsigned short)f2bf(val);
}

// ---------------------------------------------------------------------------
// Kernel 2: vp[split][64][8256] = h[64][Kslice] @ out_w[8256][Kslice]^T
// Single-barrier double-buffered pipeline: step s+1's global loads (w fp32 +
// A bf16 fragments) are issued BEFORE the barrier and stay in flight across
// it (raw s_barrier + lgkmcnt-only wait; __syncthreads would drain vmcnt(0)
// and re-serialize every step on HBM latency — that was the 0.8 TB/s bug).
// Epilogue: plain stores into per-split partial buffers (no atomics).
// ---------------------------------------------------------------------------
__global__ __launch_bounds__(256, 4) void gemm_kernel(
    const unsigned short* __restrict__ hsw, // [K8][64][8] bf16
    const float* __restrict__ w,            // [N_TRI][K_DIM] fp32
    float* __restrict__ vp)                 // [KSPLIT][64][N_TRI] fp32
{
    __shared__ __align__(16) short Bs[2][64 * 40];  // double-buffered, stride 40

    const int n0    = blockIdx.x * BN;
    const int split = blockIdx.y;
    const int s0 = (NSTEPS * split) / KSPLIT;
    const int s1 = (NSTEPS * (split + 1)) / KSPLIT;

    const int t    = threadIdx.x;
    const int lane = t & 63;
    const int wv   = t >> 6;
    const int quad = lane >> 4;
    const int l16  = lane & 15;

    const int mh = (wv >> 1) * 32;   // wave's m-origin (0 or 32)
    const int nq = (wv & 1) * 32;    // wave's n-origin within block (0 or 32)

    // B staging: 4 threads per row, 8 consecutive k each (32B contiguous)
    const int brow = t >> 2;
    const int bk   = (t & 3) * 8;

    // LDS fragment offsets (shorts)
    const int boff0 = (nq + l16) * 40 + quad * 8;
    const int boff1 = (nq + 16 + l16) * 40 + quad * 8;

    const float* wrow = w + (size_t)(n0 + brow) * K_DIM + bk;

    floatx4 acc00 = {0.f,0.f,0.f,0.f}, acc01 = {0.f,0.f,0.f,0.f};
    floatx4 acc10 = {0.f,0.f,0.f,0.f}, acc11 = {0.f,0.f,0.f,0.f};

    // prefetch registers (hold step s+1 data while step s computes)
    float  bv[8];
    short8 a0n, a1n;

    // ---- prologue: prefetch step s0
    {
        const int k0 = s0 * BK;
        const float* wp = wrow + k0;
        if (k0 + BK <= K_DIM) {
            float4 x0 = *(const float4*)wp;
            float4 x1 = *(const float4*)(wp + 4);
            bv[0]=x0.x; bv[1]=x0.y; bv[2]=x0.z; bv[3]=x0.w;
            bv[4]=x1.x; bv[5]=x1.y; bv[6]=x1.z; bv[7]=x1.w;
        } else {
#pragma unroll
            for (int q = 0; q < 8; ++q)
                bv[q] = (k0 + bk + q < K_DIM) ? wp[q] : 0.f;
        }
        const unsigned short* ap = hsw + (size_t)(s0 * 4 + quad) * (64 * 8);
        a0n = *(const short8*)(ap + (mh + l16) * 8);
        a1n = *(const short8*)(ap + (mh + 16 + l16) * 8);
    }

    int cur = 0;
    for (int s = s0; s < s1; ++s) {
        // ---- consume prefetch: convert B to bf16, grab A fragments
        short8 bs8;
#pragma unroll
        for (int q = 0; q < 8; ++q) bs8[q] = f2bf(bv[q]);
        short8 a0 = a0n, a1 = a1n;

        // ---- stage current B tile
        *(short8*)(&Bs[cur][brow * 40 + bk]) = bs8;

        // ---- issue next step's global loads (fly across barrier + MFMAs)
        if (s + 1 < s1) {
            const int k0 = (s + 1) * BK;
            const float* wp = wrow + k0;
            if (k0 + BK <= K_DIM) {
                float4 x0 = *(const float4*)wp;
                float4 x1 = *(const float4*)(wp + 4);
                bv[0]=x0.x; bv[1]=x0.y; bv[2]=x0.z; bv[3]=x0.w;
                bv[4]=x1.x; bv[5]=x1.y; bv[6]=x1.z; bv[7]=x1.w;
            } else {
#pragma unroll
                for (int q = 0; q < 8; ++q)
                    bv[q] = (k0 + bk + q < K_DIM) ? wp[q] : 0.f;
            }
            const unsigned short* ap = hsw + (size_t)((s + 1) * 4 + quad) * (64 * 8);
            a0n = *(const short8*)(ap + (mh + l16) * 8);
            a1n = *(const short8*)(ap + (mh + 16 + l16) * 8);
        }

        // ---- LDS-only drain + raw barrier (no vmcnt drain: prefetch stays
        //      in flight). "memory" clobber pins LDS ops on their side.
        asm volatile("s_waitcnt lgkmcnt(0)" ::: "memory");
        __builtin_amdgcn_s_barrier();

        short8 b0 = *(const short8*)(&Bs[cur][boff0]);
        short8 b1 = *(const short8*)(&Bs[cur][boff1]);

        acc00 = __builtin_amdgcn_mfma_f32_16x16x32_bf16(a0, b0, acc00, 0, 0, 0);
        acc01 = __builtin_amdgcn_mfma_f32_16x16x32_bf16(a0, b1, acc01, 0, 0, 0);
        acc10 = __builtin_amdgcn_mfma_f32_16x16x32_bf16(a1, b0, acc10, 0, 0, 0);
        acc11 = __builtin_amdgcn_mfma_f32_16x16x32_bf16(a1, b1, acc11, 0, 0, 0);

        cur ^= 1;
    }

    // ---- epilogue: plain stores into this split's partial buffer
    float* vout = vp + (size_t)split * (B_SZ * N_TRI);
    const int nc = n0 + nq + l16;
#pragma unroll
    for (int r = 0; r < 4; ++r) {
        int m = mh + quad * 4 + r;
        vout[(size_t)m * N_TRI + nc]             = acc00[r];
        vout[(size_t)m * N_TRI + nc + 16]        = acc01[r];
        vout[(size_t)(m + 16) * N_TRI + nc]      = acc10[r];
        vout[(size_t)(m + 16) * N_TRI + nc + 16] = acc11[r];
    }
}

// ---------------------------------------------------------------------------
// Kernel 2b: reduce the KSPLIT partials: v[e] = sum_k vp[k][e]
// 34 MB read + 2 MB write, float4-vectorized: ~6 us.
// ---------------------------------------------------------------------------
__global__ __launch_bounds__(256) void reduce_kernel(
    const float* __restrict__ vp,   // [KSPLIT][64*N_TRI]
    float* __restrict__ v)          // [64*N_TRI]
{
    int t = blockIdx.x * 256 + threadIdx.x;     // < 64*N_TRI/4
    const float4* p = (const float4*)vp + t;
    float4 s = {0.f, 0.f, 0.f, 0.f};
#pragma unroll
    for (int k = 0; k < KSPLIT; ++k) {
        float4 x = p[(size_t)k * (B_SZ * N_TRI / 4)];
        s.x += x.x; s.y += x.y; s.z += x.z; s.w += x.w;
    }
    ((float4*)v)[t] = s;
}

// ---------------------------------------------------------------------------
// Kernel 3: symmetric triu scatter + bias: y[b][i][j] = v[b][tri(min,max)] + ob
// ---------------------------------------------------------------------------
__global__ __launch_bounds__(256) void scatter_kernel(
    const float* __restrict__ v,      // [64][N_TRI]
    const float* __restrict__ out_b,  // [N_TRI]
    float* __restrict__ y)            // [64][1][128][128]
{
    int t = blockIdx.x * 256 + threadIdx.x;  // < 64*16384
    int b  = t >> 14;
    int ij = t & 16383;
    int i = ij >> 7, j = ij & 127;
    int ii = min(i, j), jj = max(i, j);
    int tri = ii * N_OUT - ((ii * (ii - 1)) >> 1) + (jj - ii);
    y[t] = v[(size_t)b * N_TRI + tri] + out_b[tri];
}

// ---------------------------------------------------------------------------
extern "C" void kernel_launch(void* const* d_in, const int* in_sizes, int n_in,
                              void* d_out, int out_size, void* d_ws, size_t ws_size,
                              hipStream_t stream) {
    const float* x   = (const float*)d_in[0];
    const float* c1w = (const float*)d_in[1];
    const float* c1b = (const float*)d_in[2];
    const float* c2w = (const float*)d_in[3];
    const float* c2b = (const float*)d_in[4];
    const float* ow  = (const float*)d_in[5];
    const float* ob  = (const float*)d_in[6];
    float* y = (float*)d_out;

    // workspace layout:
    //   hsw bf16 [K8][64][8]                    2,035,712 B
    //   vp  fp32 [KSPLIT][64][N_TRI]           33,816,576 B
    //   v   fp32 [64][N_TRI]                    2,113,536 B
    unsigned short* hsw = (unsigned short*)d_ws;
    float* vp = (float*)((char*)d_ws + (size_t)K8 * 64 * 8 * 2);
    float* v  = vp + (size_t)KSPLIT * B_SZ * N_TRI;

    conv_kernel<<<(K8 * 64 * 8) / 256, 256, 0, stream>>>(x, c1w, c1b, c2w, c2b, hsw);
    gemm_kernel<<<dim3(N_TRI / BN, KSPLIT), 256, 0, stream>>>(hsw, ow, vp);
    reduce_kernel<<<(B_SZ * N_TRI / 4) / 256, 256, 0, stream>>>(vp, v);
    scatter_kernel<<<(B_SZ * N_OUT * N_OUT) / 256, 256, 0, stream>>>(v, ob, y);
}